// Round 1
// baseline (2759.320 us; speedup 1.0000x reference)
//
#include <hip/hip_runtime.h>

#define DIM    192
#define HEADS  6
#define HD     32
#define NTOK   49
#define NWIN   64
#define QSTR   36   // padded LDS stride for q/k/v rows (conflict-free, 16B-aligned)
#define SSTR   52   // padded LDS stride for score rows

// ---------------- K1: relative-position-bias gather ----------------
// bias[h*49*49 + i*49 + j] = rpb_table[rpi[i*49+j]][h]
// rpi is declared int64 in the reference; harness doc says integers arrive as
// int32. Sniff the encoding: for little-endian int64 with values <169, every
// odd int32 word is 0. Deterministic per dataset -> graph-safe.
__global__ void wa_bias_kernel(const int* __restrict__ rpi,
                               const float* __restrict__ rpb,
                               float* __restrict__ bias) {
    __shared__ int is64_s;
    if (threadIdx.x == 0) {
        int zeros = 0;
        for (int p = 0; p < 64; ++p) zeros += (rpi[2 * p + 1] == 0) ? 1 : 0;
        is64_s = (zeros >= 48) ? 1 : 0;
    }
    __syncthreads();
    const int is64 = is64_s;
    const int total = HEADS * NTOK * NTOK;
    for (int idx = blockIdx.x * blockDim.x + threadIdx.x; idx < total;
         idx += gridDim.x * blockDim.x) {
        int h  = idx / (NTOK * NTOK);
        int nm = idx - h * (NTOK * NTOK);
        int r  = is64 ? rpi[2 * nm] : rpi[nm];
        bias[idx] = rpb[r * HEADS + h];
    }
}

// ---------------- K2: fused QKV + attention per (window, head) ----------------
__global__ __launch_bounds__(256, 2)
void wa_attn_kernel(const float* __restrict__ x,
                    const float* __restrict__ maskp,
                    const float* __restrict__ qkv_w,
                    const float* __restrict__ qkv_b,
                    const float* __restrict__ biasp,
                    float* __restrict__ out) {
    __shared__ __attribute__((aligned(16))) float sx[NTOK * DIM];      // 37632 B, aliased by S later
    __shared__ __attribute__((aligned(16))) float sqkv[3 * NTOK * QSTR]; // 21168 B
    __shared__ float sinv[NTOK];

    const int tid = threadIdx.x;
    const int bw  = blockIdx.x;
    const int h   = blockIdx.y;
    const int win = bw & (NWIN - 1);

    // ---- phase 0: stage x window (coalesced float4) ----
    {
        const float4* xw = (const float4*)(x + (size_t)bw * (NTOK * DIM));
        float4* sx4 = (float4*)sx;
        #pragma unroll
        for (int it = 0; it < 10; ++it) {
            int idx = tid + it * 256;
            if (idx < NTOK * DIM / 4) sx4[idx] = xw[idx];
        }
    }
    __syncthreads();

    // ---- phase 1: q,k,v for this head ----
    // 192 working threads: each owns one output column (sel,d) and half the
    // tokens; weight row held in registers via k-contiguous global float4s.
    if (tid < 192) {
        const int half = tid / 96;
        const int c    = tid % 96;
        const int sel  = c >> 5;
        const int d    = c & 31;
        const int col  = sel * DIM + h * HD + d;
        const int t0   = half ? 25 : 0;
        const int tn   = half ? 24 : 25;
        float acc[25];
        #pragma unroll
        for (int i = 0; i < 25; ++i) acc[i] = 0.f;
        const float4* wrow = (const float4*)(qkv_w + col * DIM);
        for (int k4 = 0; k4 < DIM / 4; ++k4) {
            float4 w4 = wrow[k4];
            #pragma unroll
            for (int i = 0; i < 25; ++i) {
                if (i < tn) {
                    float4 a4 = *(const float4*)&sx[(t0 + i) * DIM + k4 * 4];
                    acc[i] += fmaf(a4.x, w4.x, fmaf(a4.y, w4.y, fmaf(a4.z, w4.z, a4.w * w4.w)));
                }
            }
        }
        const float bb = qkv_b[col];
        #pragma unroll
        for (int i = 0; i < 25; ++i) {
            if (i < tn) sqkv[sel * (NTOK * QSTR) + (t0 + i) * QSTR + d] = acc[i] + bb;
        }
    }
    __syncthreads();

    // ---- phase 2: S = scale * q k^T + bias + mask  (S aliases sx) ----
    float* S = sx;
    {
        const int j  = tid & 63;
        const int ig = tid >> 6;
        if (j < NTOK) {
            float kreg[HD];
            #pragma unroll
            for (int d4 = 0; d4 < 8; ++d4)
                *(float4*)&kreg[d4 * 4] = *(const float4*)&sqkv[NTOK * QSTR + j * QSTR + d4 * 4];
            const float* biash = biasp + h * (NTOK * NTOK);
            const float* maskw = maskp + win * (NTOK * NTOK);
            #pragma unroll
            for (int ii = 0; ii < 13; ++ii) {
                int i = ig * 13 + ii;
                if (i < NTOK) {
                    float dot = 0.f;
                    #pragma unroll
                    for (int d4 = 0; d4 < 8; ++d4) {
                        float4 q4 = *(const float4*)&sqkv[i * QSTR + d4 * 4];
                        dot = fmaf(q4.x, kreg[d4 * 4 + 0], dot);
                        dot = fmaf(q4.y, kreg[d4 * 4 + 1], dot);
                        dot = fmaf(q4.z, kreg[d4 * 4 + 2], dot);
                        dot = fmaf(q4.w, kreg[d4 * 4 + 3], dot);
                    }
                    S[i * SSTR + j] = dot * 0.17677669529663687f
                                    + biash[i * NTOK + j] + maskw[i * NTOK + j];
                }
            }
        }
    }
    __syncthreads();

    // ---- phase 3: softmax rows (fp32, fast exp) ----
    if (tid < NTOK) {
        const int i = tid;
        float m = -1e30f;
        for (int j = 0; j < NTOK; ++j) m = fmaxf(m, S[i * SSTR + j]);
        float sum = 0.f;
        for (int j = 0; j < NTOK; ++j) {
            float e = __expf(S[i * SSTR + j] - m);
            S[i * SSTR + j] = e;
            sum += e;
        }
        sinv[i] = 1.f / sum;
    }
    __syncthreads();

    // ---- phase 4: O = P V, write pre-proj output into d_out ----
    {
        const int d4 = tid & 7;
        const int g  = tid >> 3;          // 0..31
        const int i0 = g * 2;
        const int i1 = i0 + 1;
        if (i0 < NTOK) {
            const bool has1 = (i1 < NTOK);
            float o0x = 0.f, o0y = 0.f, o0z = 0.f, o0w = 0.f;
            float o1x = 0.f, o1y = 0.f, o1z = 0.f, o1w = 0.f;
            for (int j = 0; j < NTOK; ++j) {
                float4 v4 = *(const float4*)&sqkv[2 * (NTOK * QSTR) + j * QSTR + d4 * 4];
                float p0 = S[i0 * SSTR + j];
                o0x = fmaf(p0, v4.x, o0x);
                o0y = fmaf(p0, v4.y, o0y);
                o0z = fmaf(p0, v4.z, o0z);
                o0w = fmaf(p0, v4.w, o0w);
                if (has1) {
                    float p1 = S[i1 * SSTR + j];
                    o1x = fmaf(p1, v4.x, o1x);
                    o1y = fmaf(p1, v4.y, o1y);
                    o1z = fmaf(p1, v4.z, o1z);
                    o1w = fmaf(p1, v4.w, o1w);
                }
            }
            {
                float s0 = sinv[i0];
                float4 st = { o0x * s0, o0y * s0, o0z * s0, o0w * s0 };
                *(float4*)&out[((size_t)bw * NTOK + i0) * DIM + h * HD + d4 * 4] = st;
            }
            if (has1) {
                float s1 = sinv[i1];
                float4 st = { o1x * s1, o1y * s1, o1z * s1, o1w * s1 };
                *(float4*)&out[((size_t)bw * NTOK + i1) * DIM + h * HD + d4 * 4] = st;
            }
        }
    }
}

// ---------------- K3: output projection, in place on d_out ----------------
// Each block owns 64 complete rows: reads them into LDS first, so in-place
// writes are race-free (no other block touches these rows).
__global__ __launch_bounds__(256, 3)
void wa_proj_kernel(const float* __restrict__ proj_w,
                    const float* __restrict__ proj_b,
                    float* __restrict__ out) {
    __shared__ __attribute__((aligned(16))) float As[64 * DIM];  // 48 KB
    const int tid = threadIdx.x;
    const size_t row0 = (size_t)blockIdx.x * 64;
    {
        const float4* src = (const float4*)(out + row0 * DIM);
        float4* dst = (float4*)As;
        #pragma unroll
        for (int it = 0; it < 12; ++it) dst[tid + it * 256] = src[tid + it * 256];
    }
    __syncthreads();
    const int jg = tid & 31;   // owns cols j = jg + 32*c (coalesced stores)
    const int mg = tid >> 5;   // owns rows m = mg*8 .. +7
    float acc[8][6];
    #pragma unroll
    for (int r = 0; r < 8; ++r)
        #pragma unroll
        for (int c = 0; c < 6; ++c) acc[r][c] = 0.f;

    for (int k4 = 0; k4 < DIM / 4; ++k4) {
        float4 wv[6];
        #pragma unroll
        for (int c = 0; c < 6; ++c)
            wv[c] = *(const float4*)&proj_w[(jg + c * 32) * DIM + k4 * 4];
        #pragma unroll
        for (int r = 0; r < 8; ++r) {
            float4 a4 = *(const float4*)&As[(mg * 8 + r) * DIM + k4 * 4];
            #pragma unroll
            for (int c = 0; c < 6; ++c) {
                acc[r][c] = fmaf(a4.x, wv[c].x, acc[r][c]);
                acc[r][c] = fmaf(a4.y, wv[c].y, acc[r][c]);
                acc[r][c] = fmaf(a4.z, wv[c].z, acc[r][c]);
                acc[r][c] = fmaf(a4.w, wv[c].w, acc[r][c]);
            }
        }
    }
    #pragma unroll
    for (int r = 0; r < 8; ++r) {
        const size_t m = row0 + (size_t)(mg * 8 + r);
        #pragma unroll
        for (int c = 0; c < 6; ++c) {
            int j = jg + c * 32;
            out[m * DIM + j] = acc[r][c] + proj_b[j];
        }
    }
}

extern "C" void kernel_launch(void* const* d_in, const int* in_sizes, int n_in,
                              void* d_out, int out_size, void* d_ws, size_t ws_size,
                              hipStream_t stream) {
    const float* x      = (const float*)d_in[0];
    const int*   rpi    = (const int*)d_in[1];
    const float* maskp  = (const float*)d_in[2];
    const float* qkv_w  = (const float*)d_in[3];
    const float* qkv_b  = (const float*)d_in[4];
    const float* proj_w = (const float*)d_in[5];
    const float* proj_b = (const float*)d_in[6];
    const float* rpb    = (const float*)d_in[7];
    float* out  = (float*)d_out;
    float* bias = (float*)d_ws;   // 6*49*49*4 = 57.6 KB of workspace

    wa_bias_kernel<<<30, 256, 0, stream>>>(rpi, rpb, bias);
    wa_attn_kernel<<<dim3(4096, HEADS), 256, 0, stream>>>(x, maskp, qkv_w, qkv_b, bias, out);
    wa_proj_kernel<<<(4096 * NTOK) / 64, 256, 0, stream>>>(proj_w, proj_b, out);
}

// Round 2
// 1671.267 us; speedup vs baseline: 1.6510x; 1.6510x over previous
//
#include <hip/hip_runtime.h>

#define DIM    192
#define HEADS  6
#define NTOK   49
#define NWIN   64

typedef __attribute__((ext_vector_type(8))) short short8;
typedef __attribute__((ext_vector_type(4))) float f32x4;

// LDS strides (elements). All bf16 row strides give 16B-aligned ds_read_b128
// (stride*2 % 16 == 0) and bank stride 4 (2-way conflict = free per m136).
#define XS 200   // sx / sq / sk row stride (bf16), 192 cols + pad
#define VS 72    // sv (V^T) row stride (bf16), 64 tokens + pad
#define SS 65    // S row stride (fp32)
#define PS 72    // P row stride (bf16)

#define BIAS_ELEMS (HEADS * NTOK * NTOK)             // 14406 floats
#define WQKV_SOFF   28864                            // ushort offset in ws (57728 B)
#define WQKV_ELEMS  (3 * DIM * DIM)                  // 110592
#define WPROJ_SOFF  (WQKV_SOFF + WQKV_ELEMS)         // 139456
#define WPROJ_ELEMS (DIM * DIM)                      // 36864

__device__ __forceinline__ unsigned short f2bf(float f) {
    unsigned int u = __float_as_uint(f);
    u += 0x7FFFu + ((u >> 16) & 1u);   // round-to-nearest-even
    return (unsigned short)(u >> 16);
}

// ---------------- K1: bias gather + bf16 weight conversion ----------------
__global__ void wa_prep_kernel(const int* __restrict__ rpi,
                               const float* __restrict__ rpb,
                               const float* __restrict__ qkv_w,
                               const float* __restrict__ proj_w,
                               float* __restrict__ bias,
                               unsigned short* __restrict__ wqkv,
                               unsigned short* __restrict__ wproj) {
    __shared__ int is64_s;
    if (threadIdx.x == 0) {
        int zeros = 0;
        for (int p = 0; p < 64; ++p) zeros += (rpi[2 * p + 1] == 0) ? 1 : 0;
        is64_s = (zeros >= 48) ? 1 : 0;
    }
    __syncthreads();
    const int is64 = is64_s;
    const int total = BIAS_ELEMS + WQKV_ELEMS + WPROJ_ELEMS;
    for (int idx = blockIdx.x * blockDim.x + threadIdx.x; idx < total;
         idx += gridDim.x * blockDim.x) {
        if (idx < BIAS_ELEMS) {
            int h  = idx / (NTOK * NTOK);
            int nm = idx - h * (NTOK * NTOK);
            int r  = is64 ? rpi[2 * nm] : rpi[nm];
            bias[idx] = rpb[r * HEADS + h];
        } else if (idx < BIAS_ELEMS + WQKV_ELEMS) {
            int i = idx - BIAS_ELEMS;
            wqkv[i] = f2bf(qkv_w[i]);
        } else {
            int i = idx - BIAS_ELEMS - WQKV_ELEMS;
            wproj[i] = f2bf(proj_w[i]);
        }
    }
}

// ---------------- K2: fused QKV + attention, one block per window ----------------
__global__ __launch_bounds__(512, 1)
void wa_attn_kernel(const float* __restrict__ x,
                    const float* __restrict__ maskp,
                    const unsigned short* __restrict__ wqkv,
                    const float* __restrict__ qkv_b,
                    const float* __restrict__ biasp,
                    float* __restrict__ out) {
    // union region: phase<=1 uses sx (25600 B); phase 2 uses S (16640 B) + P (9216 B)
    __shared__ __attribute__((aligned(16))) float uSP[64 * SS + 64 * (PS / 2)]; // 25856 B
    __shared__ __attribute__((aligned(16))) unsigned short sq[64 * XS];   // 25600 B
    __shared__ __attribute__((aligned(16))) unsigned short sk[64 * XS];   // 25600 B
    __shared__ __attribute__((aligned(16))) unsigned short sv[DIM * VS];  // 27648 B (V^T)
    __shared__ float sinv[64];

    unsigned short* sx = (unsigned short*)uSP;
    float* S = uSP;
    unsigned short* P = (unsigned short*)(uSP + 64 * SS);

    const int tid  = threadIdx.x;
    const int wave = tid >> 6;
    const int lane = tid & 63;
    const int quad = lane >> 4;
    const int l16  = lane & 15;
    const int bw   = blockIdx.x;
    const int win  = bw & (NWIN - 1);

    // ---- phase 0: stage x window fp32 -> bf16 LDS, zero pad rows 49..63 ----
    {
        const float4* xw = (const float4*)(x + (size_t)bw * (NTOK * DIM));
        for (int idx = tid; idx < NTOK * DIM / 4; idx += 512) {
            int row = idx / 48, c4 = idx - row * 48;
            float4 v = xw[idx];
            unsigned int lo = (unsigned int)f2bf(v.x) | ((unsigned int)f2bf(v.y) << 16);
            unsigned int hi = (unsigned int)f2bf(v.z) | ((unsigned int)f2bf(v.w) << 16);
            *(uint2*)&sx[row * XS + c4 * 4] = make_uint2(lo, hi);
        }
        for (int idx = tid; idx < 15 * 24; idx += 512) {
            int row = 49 + idx / 24, c8 = idx - (idx / 24) * 24;
            *(uint4*)&sx[row * XS + c8 * 8] = make_uint4(0, 0, 0, 0);
        }
    }
    __syncthreads();

    // ---- phase 1: QKV = X * Wqkv^T + b  (MFMA; B-frags from L2-resident bf16 weights) ----
    {
        const int ntn = (wave < 4) ? 5 : 4;   // 36 N-tiles over 8 waves
        f32x4 acc[5][4];
        for (int r = 0; r < 5; ++r)
            for (int mt = 0; mt < 4; ++mt) acc[r][mt] = (f32x4){0.f, 0.f, 0.f, 0.f};
        for (int k0 = 0; k0 < DIM; k0 += 32) {
            short8 af[4];
            #pragma unroll
            for (int mt = 0; mt < 4; ++mt)
                af[mt] = *(const short8*)&sx[(mt * 16 + l16) * XS + k0 + quad * 8];
            for (int r = 0; r < ntn; ++r) {
                int n0 = (wave + 8 * r) * 16;
                short8 bf = *(const short8*)(wqkv + (n0 + l16) * DIM + k0 + quad * 8);
                #pragma unroll
                for (int mt = 0; mt < 4; ++mt)
                    acc[r][mt] = __builtin_amdgcn_mfma_f32_16x16x32_bf16(af[mt], bf, acc[r][mt], 0, 0, 0);
            }
        }
        for (int r = 0; r < ntn; ++r) {
            int n0  = (wave + 8 * r) * 16;
            int col = n0 + l16;
            float cb = qkv_b[col];
            #pragma unroll
            for (int mt = 0; mt < 4; ++mt) {
                #pragma unroll
                for (int rr = 0; rr < 4; ++rr) {
                    int m = mt * 16 + quad * 4 + rr;    // C/D: row=quad*4+reg, col=l16
                    unsigned short bv = f2bf(acc[r][mt][rr] + cb);
                    if (col < 192)      sq[m * XS + col] = bv;
                    else if (col < 384) sk[m * XS + (col - 192)] = bv;
                    else                sv[(col - 384) * VS + m] = bv;   // V transposed
                }
            }
        }
    }
    __syncthreads();

    const float scale = 0.17677669529663687f;
    const float* maskw = maskp + win * (NTOK * NTOK);

    for (int h = 0; h < HEADS; ++h) {
        // ---- 2a: S = scale * Q_h K_h^T + bias + mask (16 tiles, 2 per wave) ----
        {
            f32x4 zz = {0.f, 0.f, 0.f, 0.f};
            const float* bh = biasp + h * (NTOK * NTOK);
            #pragma unroll
            for (int tt = 0; tt < 2; ++tt) {
                int t = wave * 2 + tt;
                int mt = t >> 2, nt = t & 3;
                short8 af = *(const short8*)&sq[(mt * 16 + l16) * XS + h * 32 + quad * 8];
                short8 bf = *(const short8*)&sk[(nt * 16 + l16) * XS + h * 32 + quad * 8];
                f32x4 d = __builtin_amdgcn_mfma_f32_16x16x32_bf16(af, bf, zz, 0, 0, 0);
                #pragma unroll
                for (int rr = 0; rr < 4; ++rr) {
                    int i = mt * 16 + quad * 4 + rr;
                    int j = nt * 16 + l16;
                    float sval = -30000.f;   // pad -> exp underflows to 0
                    if (i < NTOK && j < NTOK)
                        sval = d[rr] * scale + bh[i * NTOK + j] + maskw[i * NTOK + j];
                    S[i * SS + j] = sval;
                }
            }
        }
        __syncthreads();
        // ---- 2b: softmax rows (8 threads/row) -> bf16 P (unnormalized), sinv ----
        if (tid < 392) {
            int i = tid >> 3, s = tid & 7;
            float m = -1e30f;
            for (int jj = 0; jj < 7; ++jj) {
                int j = s + 8 * jj;
                if (j < NTOK) m = fmaxf(m, S[i * SS + j]);
            }
            for (int o = 1; o < 8; o <<= 1) m = fmaxf(m, __shfl_xor(m, o));
            float sum = 0.f;
            for (int jj = 0; jj < 8; ++jj) {
                int j = s + 8 * jj;                    // covers 0..63 (pads -> 0)
                float e = 0.f;
                if (j < NTOK) { e = __expf(S[i * SS + j] - m); sum += e; }
                P[i * PS + j] = f2bf(e);
            }
            for (int o = 1; o < 8; o <<= 1) sum += __shfl_xor(sum, o);
            if (s == 0) sinv[i] = 1.f / sum;
        }
        __syncthreads();
        // ---- 2c: O = (P V) * sinv, direct global store (8 tiles, 1 per wave) ----
        {
            int mt = wave >> 1, nt = wave & 1;
            f32x4 acc = {0.f, 0.f, 0.f, 0.f};
            #pragma unroll
            for (int k0 = 0; k0 < 64; k0 += 32) {
                short8 af = *(const short8*)&P[(mt * 16 + l16) * PS + k0 + quad * 8];
                short8 bf = *(const short8*)&sv[(h * 32 + nt * 16 + l16) * VS + k0 + quad * 8];
                acc = __builtin_amdgcn_mfma_f32_16x16x32_bf16(af, bf, acc, 0, 0, 0);
            }
            #pragma unroll
            for (int rr = 0; rr < 4; ++rr) {
                int i = mt * 16 + quad * 4 + rr;
                if (i < NTOK)
                    out[((size_t)bw * NTOK + i) * DIM + h * 32 + nt * 16 + l16] = acc[rr] * sinv[i];
            }
        }
        // no end-of-loop barrier needed: next 2a writes S only (disjoint from P/sv/sinv);
        // the post-2a barrier orders this 2c's P/sinv reads before next 2b's writes.
    }
}

// ---------------- K3: in-place output projection (MFMA) ----------------
__global__ __launch_bounds__(256, 2)
void wa_proj_kernel(const unsigned short* __restrict__ wproj,
                    const float* __restrict__ proj_b,
                    float* __restrict__ out) {
    __shared__ __attribute__((aligned(16))) unsigned short sA[64 * XS];  // 25600 B
    const int tid  = threadIdx.x;
    const int wave = tid >> 6;
    const int lane = tid & 63;
    const int quad = lane >> 4;
    const int l16  = lane & 15;
    const size_t row0 = (size_t)blockIdx.x * 64;
    {
        const float4* src = (const float4*)(out + row0 * DIM);
        for (int idx = tid; idx < 64 * 48; idx += 256) {
            int row = idx / 48, c4 = idx - row * 48;
            float4 v = src[idx];
            unsigned int lo = (unsigned int)f2bf(v.x) | ((unsigned int)f2bf(v.y) << 16);
            unsigned int hi = (unsigned int)f2bf(v.z) | ((unsigned int)f2bf(v.w) << 16);
            *(uint2*)&sA[row * XS + c4 * 4] = make_uint2(lo, hi);
        }
    }
    __syncthreads();
    f32x4 acc[3][4];
    for (int r = 0; r < 3; ++r)
        for (int mt = 0; mt < 4; ++mt) acc[r][mt] = (f32x4){0.f, 0.f, 0.f, 0.f};
    for (int k0 = 0; k0 < DIM; k0 += 32) {
        short8 af[4];
        #pragma unroll
        for (int mt = 0; mt < 4; ++mt)
            af[mt] = *(const short8*)&sA[(mt * 16 + l16) * XS + k0 + quad * 8];
        #pragma unroll
        for (int r = 0; r < 3; ++r) {
            int n0 = (wave + 4 * r) * 16;
            short8 bf = *(const short8*)(wproj + (n0 + l16) * DIM + k0 + quad * 8);
            #pragma unroll
            for (int mt = 0; mt < 4; ++mt)
                acc[r][mt] = __builtin_amdgcn_mfma_f32_16x16x32_bf16(af[mt], bf, acc[r][mt], 0, 0, 0);
        }
    }
    #pragma unroll
    for (int r = 0; r < 3; ++r) {
        int n0 = (wave + 4 * r) * 16;
        float cb = proj_b[n0 + l16];
        #pragma unroll
        for (int mt = 0; mt < 4; ++mt) {
            #pragma unroll
            for (int rr = 0; rr < 4; ++rr) {
                int m = mt * 16 + quad * 4 + rr;
                out[(row0 + m) * DIM + n0 + l16] = acc[r][mt][rr] + cb;
            }
        }
    }
}

extern "C" void kernel_launch(void* const* d_in, const int* in_sizes, int n_in,
                              void* d_out, int out_size, void* d_ws, size_t ws_size,
                              hipStream_t stream) {
    const float* x      = (const float*)d_in[0];
    const int*   rpi    = (const int*)d_in[1];
    const float* maskp  = (const float*)d_in[2];
    const float* qkv_w  = (const float*)d_in[3];
    const float* qkv_b  = (const float*)d_in[4];
    const float* proj_w = (const float*)d_in[5];
    const float* proj_b = (const float*)d_in[6];
    const float* rpb    = (const float*)d_in[7];
    float* out = (float*)d_out;

    float* bias = (float*)d_ws;                                   // 57624 B
    unsigned short* wqkv  = (unsigned short*)d_ws + WQKV_SOFF;    // 221184 B
    unsigned short* wproj = (unsigned short*)d_ws + WPROJ_SOFF;   // 73728 B

    wa_prep_kernel<<<320, 256, 0, stream>>>(rpi, rpb, qkv_w, proj_w, bias, wqkv, wproj);
    wa_attn_kernel<<<4096, 512, 0, stream>>>(x, maskp, wqkv, qkv_b, bias, out);
    wa_proj_kernel<<<(4096 * NTOK) / 64, 256, 0, stream>>>(wproj, proj_b, out);
}

// Round 3
// 654.475 us; speedup vs baseline: 4.2161x; 2.5536x over previous
//
#include <hip/hip_runtime.h>

#define DIM    192
#define HEADS  6
#define NTOK   49
#define NWIN   64

typedef __attribute__((ext_vector_type(8))) short short8;
typedef __attribute__((ext_vector_type(4))) float f32x4;

// LDS strides (elements). All bf16 row strides give 16B-aligned ds_read_b128
// (stride*2 % 16 == 0) and bank stride 4 (2-way conflict = free per m136).
#define XS 200   // sx / sq / sk row stride (bf16), 192 cols + pad
#define VS 72    // sv (V^T) row stride (bf16), 64 tokens + pad
#define SS 65    // S row stride (fp32)
#define PS 72    // P row stride (bf16)

#define BIAS_ELEMS (HEADS * NTOK * NTOK)             // 14406 floats
#define WQKV_SOFF   28864                            // ushort offset in ws (57728 B)
#define WQKV_ELEMS  (3 * DIM * DIM)                  // 110592
#define WPROJ_SOFF  (WQKV_SOFF + WQKV_ELEMS)         // 139456
#define WPROJ_ELEMS (DIM * DIM)                      // 36864

__device__ __forceinline__ unsigned short f2bf(float f) {
    unsigned int u = __float_as_uint(f);
    u += 0x7FFFu + ((u >> 16) & 1u);   // round-to-nearest-even
    return (unsigned short)(u >> 16);
}

// ---------------- K1: bias gather + bf16 weight conversion ----------------
__global__ void wa_prep_kernel(const int* __restrict__ rpi,
                               const float* __restrict__ rpb,
                               const float* __restrict__ qkv_w,
                               const float* __restrict__ proj_w,
                               float* __restrict__ bias,
                               unsigned short* __restrict__ wqkv,
                               unsigned short* __restrict__ wproj) {
    __shared__ int is64_s;
    if (threadIdx.x == 0) {
        int zeros = 0;
        for (int p = 0; p < 64; ++p) zeros += (rpi[2 * p + 1] == 0) ? 1 : 0;
        is64_s = (zeros >= 48) ? 1 : 0;
    }
    __syncthreads();
    const int is64 = is64_s;
    const int total = BIAS_ELEMS + WQKV_ELEMS + WPROJ_ELEMS;
    for (int idx = blockIdx.x * blockDim.x + threadIdx.x; idx < total;
         idx += gridDim.x * blockDim.x) {
        if (idx < BIAS_ELEMS) {
            int h  = idx / (NTOK * NTOK);
            int nm = idx - h * (NTOK * NTOK);
            int r  = is64 ? rpi[2 * nm] : rpi[nm];
            bias[idx] = rpb[r * HEADS + h];
        } else if (idx < BIAS_ELEMS + WQKV_ELEMS) {
            int i = idx - BIAS_ELEMS;
            wqkv[i] = f2bf(qkv_w[i]);
        } else {
            int i = idx - BIAS_ELEMS - WQKV_ELEMS;
            wproj[i] = f2bf(proj_w[i]);
        }
    }
}

// ---------------- K2: fused QKV + attention, one block per window ----------------
__global__ __launch_bounds__(512, 1)
void wa_attn_kernel(const float* __restrict__ x,
                    const float* __restrict__ maskp,
                    const unsigned short* __restrict__ wqkv,
                    const float* __restrict__ qkv_b,
                    const float* __restrict__ biasp,
                    float* __restrict__ out) {
    // union region: phase<=1 uses sx (25600 B); phase 2 uses S (16640 B) + P (9216 B)
    __shared__ __attribute__((aligned(16))) float uSP[64 * SS + 64 * (PS / 2)]; // 25856 B
    __shared__ __attribute__((aligned(16))) unsigned short sq[64 * XS];   // 25600 B
    __shared__ __attribute__((aligned(16))) unsigned short sk[64 * XS];   // 25600 B
    __shared__ __attribute__((aligned(16))) unsigned short sv[DIM * VS];  // 27648 B (V^T)
    __shared__ float sinv[64];

    unsigned short* sx = (unsigned short*)uSP;
    float* S = uSP;
    unsigned short* P = (unsigned short*)(uSP + 64 * SS);

    const int tid  = threadIdx.x;
    const int wave = tid >> 6;
    const int lane = tid & 63;
    const int quad = lane >> 4;
    const int l16  = lane & 15;
    const int bw   = blockIdx.x;
    const int win  = bw & (NWIN - 1);

    // ---- phase 0: stage x window fp32 -> bf16 LDS, zero pad rows 49..63 ----
    {
        const float4* xw = (const float4*)(x + (size_t)bw * (NTOK * DIM));
        for (int idx = tid; idx < NTOK * DIM / 4; idx += 512) {
            int row = idx / 48, c4 = idx - row * 48;
            float4 v = xw[idx];
            unsigned int lo = (unsigned int)f2bf(v.x) | ((unsigned int)f2bf(v.y) << 16);
            unsigned int hi = (unsigned int)f2bf(v.z) | ((unsigned int)f2bf(v.w) << 16);
            *(uint2*)&sx[row * XS + c4 * 4] = make_uint2(lo, hi);
        }
        for (int idx = tid; idx < 15 * 24; idx += 512) {
            int row = 49 + idx / 24, c8 = idx - (idx / 24) * 24;
            *(uint4*)&sx[row * XS + c8 * 8] = make_uint4(0, 0, 0, 0);
        }
    }
    __syncthreads();

    // ---- phase 1: QKV = X * Wqkv^T + b  (MFMA; B-frags from L2-resident bf16 weights) ----
    // NOTE: r-loops MUST be compile-time unrolled with static acc indices;
    // a runtime trip count (round-2 bug) demoted acc[][] to scratch -> 8 GB
    // of hidden HBM traffic (WRITE_SIZE 4.1 GB, VGPR_Count 88).
    {
        f32x4 acc[5][4];
        #pragma unroll
        for (int r = 0; r < 5; ++r)
            #pragma unroll
            for (int mt = 0; mt < 4; ++mt) acc[r][mt] = (f32x4){0.f, 0.f, 0.f, 0.f};
        for (int k0 = 0; k0 < DIM; k0 += 32) {
            short8 af[4];
            #pragma unroll
            for (int mt = 0; mt < 4; ++mt)
                af[mt] = *(const short8*)&sx[(mt * 16 + l16) * XS + k0 + quad * 8];
            #pragma unroll
            for (int r = 0; r < 5; ++r) {
                if (wave >= 4 && r == 4) continue;   // 36 N-tiles over 8 waves
                int n0 = (wave + 8 * r) * 16;
                short8 bf = *(const short8*)(wqkv + (n0 + l16) * DIM + k0 + quad * 8);
                #pragma unroll
                for (int mt = 0; mt < 4; ++mt)
                    acc[r][mt] = __builtin_amdgcn_mfma_f32_16x16x32_bf16(af[mt], bf, acc[r][mt], 0, 0, 0);
            }
        }
        #pragma unroll
        for (int r = 0; r < 5; ++r) {
            if (wave >= 4 && r == 4) continue;
            int n0  = (wave + 8 * r) * 16;
            int col = n0 + l16;
            float cb = qkv_b[col];
            #pragma unroll
            for (int mt = 0; mt < 4; ++mt) {
                #pragma unroll
                for (int rr = 0; rr < 4; ++rr) {
                    int m = mt * 16 + quad * 4 + rr;    // C/D: row=quad*4+reg, col=l16
                    unsigned short bv = f2bf(acc[r][mt][rr] + cb);
                    if (col < 192)      sq[m * XS + col] = bv;
                    else if (col < 384) sk[m * XS + (col - 192)] = bv;
                    else                sv[(col - 384) * VS + m] = bv;   // V transposed
                }
            }
        }
    }
    __syncthreads();

    const float scale = 0.17677669529663687f;
    const float* maskw = maskp + win * (NTOK * NTOK);

    for (int h = 0; h < HEADS; ++h) {
        // ---- 2a: S = scale * Q_h K_h^T + bias + mask (16 tiles, 2 per wave) ----
        {
            f32x4 zz = {0.f, 0.f, 0.f, 0.f};
            const float* bh = biasp + h * (NTOK * NTOK);
            #pragma unroll
            for (int tt = 0; tt < 2; ++tt) {
                int t = wave * 2 + tt;
                int mt = t >> 2, nt = t & 3;
                short8 af = *(const short8*)&sq[(mt * 16 + l16) * XS + h * 32 + quad * 8];
                short8 bf = *(const short8*)&sk[(nt * 16 + l16) * XS + h * 32 + quad * 8];
                f32x4 d = __builtin_amdgcn_mfma_f32_16x16x32_bf16(af, bf, zz, 0, 0, 0);
                #pragma unroll
                for (int rr = 0; rr < 4; ++rr) {
                    int i = mt * 16 + quad * 4 + rr;
                    int j = nt * 16 + l16;
                    float sval = -30000.f;   // pad -> exp underflows to 0
                    if (i < NTOK && j < NTOK)
                        sval = d[rr] * scale + bh[i * NTOK + j] + maskw[i * NTOK + j];
                    S[i * SS + j] = sval;
                }
            }
        }
        __syncthreads();
        // ---- 2b: softmax rows (8 threads/row) -> bf16 P (unnormalized), sinv ----
        if (tid < 392) {
            int i = tid >> 3, s = tid & 7;
            float m = -1e30f;
            for (int jj = 0; jj < 7; ++jj) {
                int j = s + 8 * jj;
                if (j < NTOK) m = fmaxf(m, S[i * SS + j]);
            }
            for (int o = 1; o < 8; o <<= 1) m = fmaxf(m, __shfl_xor(m, o));
            float sum = 0.f;
            #pragma unroll
            for (int jj = 0; jj < 8; ++jj) {
                int j = s + 8 * jj;                    // covers 0..63 (pads -> 0)
                float e = 0.f;
                if (j < NTOK) { e = __expf(S[i * SS + j] - m); sum += e; }
                P[i * PS + j] = f2bf(e);
            }
            for (int o = 1; o < 8; o <<= 1) sum += __shfl_xor(sum, o);
            if (s == 0) sinv[i] = 1.f / sum;
        }
        __syncthreads();
        // ---- 2c: O = (P V) * sinv, direct global store (8 tiles, 1 per wave) ----
        {
            int mt = wave >> 1, nt = wave & 1;
            f32x4 acc = {0.f, 0.f, 0.f, 0.f};
            #pragma unroll
            for (int k0 = 0; k0 < 64; k0 += 32) {
                short8 af = *(const short8*)&P[(mt * 16 + l16) * PS + k0 + quad * 8];
                short8 bf = *(const short8*)&sv[(h * 32 + nt * 16 + l16) * VS + k0 + quad * 8];
                acc = __builtin_amdgcn_mfma_f32_16x16x32_bf16(af, bf, acc, 0, 0, 0);
            }
            #pragma unroll
            for (int rr = 0; rr < 4; ++rr) {
                int i = mt * 16 + quad * 4 + rr;
                if (i < NTOK)
                    out[((size_t)bw * NTOK + i) * DIM + h * 32 + nt * 16 + l16] = acc[rr] * sinv[i];
            }
        }
        // no end-of-loop barrier needed: next 2a writes S only (disjoint from P/sv/sinv);
        // the post-2a barrier orders this 2c's P/sinv reads before next 2b's writes.
    }
}

// ---------------- K3: in-place output projection (MFMA) ----------------
__global__ __launch_bounds__(256, 2)
void wa_proj_kernel(const unsigned short* __restrict__ wproj,
                    const float* __restrict__ proj_b,
                    float* __restrict__ out) {
    __shared__ __attribute__((aligned(16))) unsigned short sA[64 * XS];  // 25600 B
    const int tid  = threadIdx.x;
    const int wave = tid >> 6;
    const int lane = tid & 63;
    const int quad = lane >> 4;
    const int l16  = lane & 15;
    const size_t row0 = (size_t)blockIdx.x * 64;
    {
        const float4* src = (const float4*)(out + row0 * DIM);
        for (int idx = tid; idx < 64 * 48; idx += 256) {
            int row = idx / 48, c4 = idx - row * 48;
            float4 v = src[idx];
            unsigned int lo = (unsigned int)f2bf(v.x) | ((unsigned int)f2bf(v.y) << 16);
            unsigned int hi = (unsigned int)f2bf(v.z) | ((unsigned int)f2bf(v.w) << 16);
            *(uint2*)&sA[row * XS + c4 * 4] = make_uint2(lo, hi);
        }
    }
    __syncthreads();
    f32x4 acc[3][4];
    #pragma unroll
    for (int r = 0; r < 3; ++r)
        #pragma unroll
        for (int mt = 0; mt < 4; ++mt) acc[r][mt] = (f32x4){0.f, 0.f, 0.f, 0.f};
    for (int k0 = 0; k0 < DIM; k0 += 32) {
        short8 af[4];
        #pragma unroll
        for (int mt = 0; mt < 4; ++mt)
            af[mt] = *(const short8*)&sA[(mt * 16 + l16) * XS + k0 + quad * 8];
        #pragma unroll
        for (int r = 0; r < 3; ++r) {
            int n0 = (wave + 4 * r) * 16;
            short8 bf = *(const short8*)(wproj + (n0 + l16) * DIM + k0 + quad * 8);
            #pragma unroll
            for (int mt = 0; mt < 4; ++mt)
                acc[r][mt] = __builtin_amdgcn_mfma_f32_16x16x32_bf16(af[mt], bf, acc[r][mt], 0, 0, 0);
        }
    }
    #pragma unroll
    for (int r = 0; r < 3; ++r) {
        int n0 = (wave + 4 * r) * 16;
        float cb = proj_b[n0 + l16];
        #pragma unroll
        for (int mt = 0; mt < 4; ++mt) {
            #pragma unroll
            for (int rr = 0; rr < 4; ++rr) {
                int m = mt * 16 + quad * 4 + rr;
                out[(row0 + m) * DIM + n0 + l16] = acc[r][mt][rr] + cb;
            }
        }
    }
}

extern "C" void kernel_launch(void* const* d_in, const int* in_sizes, int n_in,
                              void* d_out, int out_size, void* d_ws, size_t ws_size,
                              hipStream_t stream) {
    const float* x      = (const float*)d_in[0];
    const int*   rpi    = (const int*)d_in[1];
    const float* maskp  = (const float*)d_in[2];
    const float* qkv_w  = (const float*)d_in[3];
    const float* qkv_b  = (const float*)d_in[4];
    const float* proj_w = (const float*)d_in[5];
    const float* proj_b = (const float*)d_in[6];
    const float* rpb    = (const float*)d_in[7];
    float* out = (float*)d_out;

    float* bias = (float*)d_ws;                                   // 57624 B
    unsigned short* wqkv  = (unsigned short*)d_ws + WQKV_SOFF;    // 221184 B
    unsigned short* wproj = (unsigned short*)d_ws + WPROJ_SOFF;   // 73728 B

    wa_prep_kernel<<<320, 256, 0, stream>>>(rpi, rpb, qkv_w, proj_w, bias, wqkv, wproj);
    wa_attn_kernel<<<4096, 512, 0, stream>>>(x, maskp, wqkv, qkv_b, bias, out);
    wa_proj_kernel<<<(4096 * NTOK) / 64, 256, 0, stream>>>(wproj, proj_b, out);
}